// Round 7
// baseline (344.442 us; speedup 1.0000x reference)
//
#include <hip/hip_runtime.h>
#include <stdint.h>

#define B_   8
#define N_   2048
#define F_   256
#define BN_  (B_ * N_)
#define ALPHA_ 0.2f

typedef __attribute__((ext_vector_type(8))) short  short8;
typedef __attribute__((ext_vector_type(4))) float  f32x4;

__device__ __forceinline__ unsigned short f2bf(float x) {
  uint32_t u = __float_as_uint(x);
  uint32_t r = (u + 0x7fffu + ((u >> 16) & 1u)) >> 16;  // RNE
  return (unsigned short)r;
}

// monotone float -> uint key (order-preserving), and inverse
__device__ __forceinline__ uint32_t fkey(float f) {
  uint32_t b = __float_as_uint(f);
  return b ^ (uint32_t)(((int32_t)b >> 31) | (int32_t)0x80000000);
}
__device__ __forceinline__ float ikey(uint32_t k) {
  uint32_t b = (k & 0x80000000u) ? (k ^ 0x80000000u) : ~k;
  return __uint_as_float(b);
}

__device__ __forceinline__ void async_load16(const void* g, void* l) {
  __builtin_amdgcn_global_load_lds(
      (const __attribute__((address_space(1))) uint32_t*)g,
      (__attribute__((address_space(3))) uint32_t*)l, 16, 0, 0);
}

// nontemporal 16B store
__device__ __forceinline__ void nt_store4(float* p, f32x4 v) {
  __builtin_nontemporal_store(v, (f32x4*)p);
}

// ---------------- W transpose to bf16 [f][k] + key-atomic init (absorbs memsets) --
__global__ void k_cvt_w(const float* __restrict__ W, unsigned short* __restrict__ WT,
                        uint32_t* __restrict__ maxk, uint32_t* __restrict__ mink) {
  int k = blockIdx.x, n = threadIdx.x;
  if (k == 0 && n < 16) { maxk[n] = 0u; mink[n] = 0xFFFFFFFFu; }
  WT[n * F_ + k] = f2bf(W[k * F_ + n]);  // WT[f][k], k contiguous (MFMA B layout)
}

// ---------------- GEMM1 v4 (kept): 64-row structure, Trans overlaid on loop
// tiles (LDS 37KB) -> 2 blocks/CU; sibling block hides staging drains. ----
__launch_bounds__(256, 2)
__global__ void k_gemm1(const float* __restrict__ inp,            // [BN][F] f32
                        const unsigned short* __restrict__ WT,    // [F][F]  bf16
                        const float* __restrict__ avec,           // [2F]
                        unsigned short* __restrict__ hT,          // [F][BN] bf16
                        float* __restrict__ s1g, float* __restrict__ s2g,
                        uint32_t* __restrict__ maxk, uint32_t* __restrict__ mink) {
  // loop phase: Atile 4KB @0, Btile 16KB @4096.  epilogue: Trans 36KB @0.
  __shared__ __align__(16) char smem[256 * 72 * 2];  // 36864 B
  __shared__ float s1_lds[64], s2_lds[64];
  unsigned short* Atile = (unsigned short*)smem;            // [64][32]
  unsigned short* Btile = (unsigned short*)(smem + 4096);   // [256][32]

  const int tid  = threadIdx.x;
  const int wave = tid >> 6, lane = tid & 63;
  const int n16  = lane & 15, quad = lane >> 4;
  const int i0   = blockIdx.x * 64;
  const int b    = i0 >> 11;  // batch (2048 rows each; 64 | 2048)

  if (tid < 64) { s1_lds[tid] = 0.0f; s2_lds[tid] = 0.0f; }

  f32x4 acc[4][4];
  #pragma unroll
  for (int mt = 0; mt < 4; ++mt)
    #pragma unroll
    for (int nt = 0; nt < 4; ++nt) acc[mt][nt] = (f32x4){0.f, 0.f, 0.f, 0.f};

  for (int k0 = 0; k0 < F_; k0 += 32) {
    {  // stage A from f32 inp: convert in-register, ds_write_b128
      int r = tid >> 2, cp = tid & 3;
      const float* gp = inp + (size_t)(i0 + r) * F_ + k0 + cp * 8;
      float4 va = *(const float4*)gp;
      float4 vb = *(const float4*)(gp + 4);
      short8 sv;
      sv[0] = (short)f2bf(va.x); sv[1] = (short)f2bf(va.y);
      sv[2] = (short)f2bf(va.z); sv[3] = (short)f2bf(va.w);
      sv[4] = (short)f2bf(vb.x); sv[5] = (short)f2bf(vb.y);
      sv[6] = (short)f2bf(vb.z); sv[7] = (short)f2bf(vb.w);
      *(short8*)((char*)Atile + r * 64 + cp * 16) = sv;
    }
    #pragma unroll
    for (int g4 = 0; g4 < 4; ++g4) {  // stage B (bf16 WT): 4 instr/wave
      int f = (wave << 6) + (g4 << 4) + (lane >> 2);
      int p = lane & 3;
      async_load16(WT + (size_t)f * F_ + k0 + p * 8,
                   (char*)Btile + wave * 4096 + g4 * 1024);
    }
    __syncthreads();

    short8 af[4], bf_[4];
    #pragma unroll
    for (int mt = 0; mt < 4; ++mt)
      af[mt] = *(const short8*)((const char*)Atile + ((mt * 16 + n16) * 64 + quad * 16));
    #pragma unroll
    for (int nt = 0; nt < 4; ++nt)
      bf_[nt] = *(const short8*)((const char*)Btile + ((wave * 64 + nt * 16 + n16) * 64 + quad * 16));
    #pragma unroll
    for (int mt = 0; mt < 4; ++mt)
      #pragma unroll
      for (int nt = 0; nt < 4; ++nt)
        acc[mt][nt] = __builtin_amdgcn_mfma_f32_16x16x32_bf16(af[mt], bf_[nt], acc[mt][nt], 0, 0, 0);
    __syncthreads();  // also orders last Btile reads before Trans overlay below
  }

  // ---- epilogue (Trans overlays loop tiles; safe after final barrier) ----
  unsigned short* Trans = (unsigned short*)smem;  // [256][72]

  #pragma unroll
  for (int mt = 0; mt < 4; ++mt)
    #pragma unroll
    for (int nt = 0; nt < 4; ++nt) {
      int f = (wave << 6) + (nt << 4) + n16;
      int i = (mt << 4) + (quad << 2);
      ushort4 pk;
      pk.x = f2bf(acc[mt][nt][0]); pk.y = f2bf(acc[mt][nt][1]);
      pk.z = f2bf(acc[mt][nt][2]); pk.w = f2bf(acc[mt][nt][3]);
      *(ushort4*)(Trans + f * 72 + i) = pk;
    }

  float a1v[4], a2v[4];
  #pragma unroll
  for (int nt = 0; nt < 4; ++nt) {
    int f = (wave << 6) + (nt << 4) + n16;
    a1v[nt] = avec[f];
    a2v[nt] = avec[F_ + f];
  }
  #pragma unroll
  for (int mt = 0; mt < 4; ++mt) {
    float s1p[4] = {0, 0, 0, 0}, s2p[4] = {0, 0, 0, 0};
    #pragma unroll
    for (int nt = 0; nt < 4; ++nt)
      #pragma unroll
      for (int rg = 0; rg < 4; ++rg) {
        s1p[rg] = fmaf(acc[mt][nt][rg], a1v[nt], s1p[rg]);
        s2p[rg] = fmaf(acc[mt][nt][rg], a2v[nt], s2p[rg]);
      }
    #pragma unroll
    for (int rg = 0; rg < 4; ++rg) {
      float v1 = s1p[rg], v2 = s2p[rg];
      #pragma unroll
      for (int off = 1; off < 16; off <<= 1) {
        v1 += __shfl_xor(v1, off);
        v2 += __shfl_xor(v2, off);
      }
      if (n16 == 0) {
        atomicAdd(&s1_lds[(mt << 4) + (quad << 2) + rg], v1);
        atomicAdd(&s2_lds[(mt << 4) + (quad << 2) + rg], v2);
      }
    }
  }
  __syncthreads();

  #pragma unroll
  for (int it = 0; it < 8; ++it) {
    int f = it * 32 + wave * 8 + (lane >> 3);
    int i = (lane & 7) * 8;
    short8 v = *(const short8*)(Trans + f * 72 + i);
    *(short8*)(hT + (size_t)f * BN_ + i0 + i) = v;
  }

  if (tid < 64) {
    float v1 = s1_lds[tid], v2 = s2_lds[tid];
    s1g[i0 + tid] = v1;
    s2g[i0 + tid] = v2;
    float mn1 = v1, mx1 = v1, mn2 = v2, mx2 = v2;
    #pragma unroll
    for (int off = 1; off < 64; off <<= 1) {
      mn1 = fminf(mn1, __shfl_xor(mn1, off));
      mx1 = fmaxf(mx1, __shfl_xor(mx1, off));
      mn2 = fminf(mn2, __shfl_xor(mn2, off));
      mx2 = fmaxf(mx2, __shfl_xor(mx2, off));
    }
    if (tid == 0) {
      atomicMax(&maxk[b * 2 + 0], fkey(mx1));
      atomicMax(&maxk[b * 2 + 1], fkey(mx2));
      atomicMin(&mink[b * 2 + 0], fkey(mn1));
      atomicMin(&mink[b * 2 + 1], fkey(mn2));
    }
  }
}

// ---------------- GEMM2 v4b: BARRIER-FREE k-loop (strides fixed vs R5).
// Wave layout 2(M)x2(N): wave (wm,wn) owns rows 16*wm..+15, cols 128*wn..+127.
// Each lane computes the att values its OWN A-fragment needs (row 16wm+n16,
// cols quad*8..+8) -> A never touches LDS; no cross-wave dependency.
// Each wave stages its 128 f-rows x 32 k = 8192 B per tile, double-buffered:
// wave segment = 16384 B. Per-wave pipeline: vmcnt(1) drains this tile's 8
// stage DMAs (keeps last att store), ds_read B frags, issue stage(t+1),
// producer VALU -> af in registers, 1 att store (wn halves split), 8 MFMA.
// Only barrier: prologue (shared s2_lds). LDS 64KB + 8KB = 72KB -> 2 blocks/CU.
__launch_bounds__(256, 2)
__global__ void k_gemm2(const unsigned short* __restrict__ hT,  // [F][BN] bf16
                        const float* __restrict__ s1, const float* __restrict__ s2,
                        const uint32_t* __restrict__ maxk, const uint32_t* __restrict__ mink,
                        float* __restrict__ hprime,  // [B][N][F]
                        float* __restrict__ att) {   // [B][N][N]
  __shared__ __align__(16) char Btile[4 * 2 * 8192];  // 4 waves x 2 bufs x 8KB = 64KB
  __shared__ __align__(16) float s2_lds[N_];          // 8 KB

  const int tid  = threadIdx.x;
  const int wave = tid >> 6, lane = tid & 63;
  const int n16  = lane & 15, quad = lane >> 4;
  const int wm   = wave >> 1, wn = wave & 1;
  const int blk  = blockIdx.x;
  const int b    = blk & 7;            // batch = blk%8 -> XCD-local hT_b in L2
  const int i0   = (blk >> 3) * 32;    // 32-row tile within batch

  float mx1 = ikey(maxk[b * 2 + 0]), mx2 = ikey(maxk[b * 2 + 1]);
  float mn1 = ikey(mink[b * 2 + 0]), mn2 = ikey(mink[b * 2 + 1]);
  float smn = mn1 + mn2, smx = mx1 + mx2;
  float emn = fmaxf(smn, ALPHA_ * smn);
  float emx = fmaxf(smx, ALPHA_ * smx);
  float scale  = 30.0f / (emx - emn);
  const float uscale = -scale;                 // u = -e_norm
  const float ubias  = emn * scale + 20.0f;

  const int   myrow = 16 * wm + n16;                         // att row this lane computes
  const float s1v   = s1[b * N_ + i0 + myrow];
  const float* s2b  = s2 + b * N_;
  float* attrow = att + ((size_t)(b * N_ + i0 + myrow)) * N_;

  char* wseg = Btile + wave * 16384;  // this wave's 2-buffer segment (2 x 8192 B)

  auto stage_b = [&](int buf_, int k0_) {
    #pragma unroll
    for (int g = 0; g < 8; ++g) {  // 8 instr/wave: 128 f-rows x 32 k, 64B-contiguous
      int f = 128 * wn + g * 16 + (lane >> 2);
      int p = lane & 3;
      async_load16(hT + (size_t)f * BN_ + b * N_ + k0_ + p * 8,
                   wseg + buf_ * 8192 + g * 1024);
    }
  };

  // ---- prologue: s2 row (oldest) + stage(0); drain s2, barrier, drain stage(0) ----
  #pragma unroll
  for (int it = 0; it < 2; ++it)
    async_load16(s2b + wave * 512 + it * 256 + lane * 4,
                 (char*)s2_lds + wave * 2048 + it * 1024);
  stage_b(0, 0);
  asm volatile("s_waitcnt vmcnt(8)" ::: "memory");  // s2 done; stage(0) in flight
  __builtin_amdgcn_s_barrier();                     // s2_lds visible to all waves
  asm volatile("s_waitcnt vmcnt(0)" ::: "memory");  // stage(0) done (one-time)

  f32x4 acc[8];
  #pragma unroll
  for (int nt = 0; nt < 8; ++nt) acc[nt] = (f32x4){0.f, 0.f, 0.f, 0.f};

  for (int t = 0; t < 64; ++t) {
    const int cur = t & 1;
    const int k0  = t << 5;

    // drain this tile's 8 stage DMAs (oldest); keep last att store in flight
    asm volatile("s_waitcnt vmcnt(1)" ::: "memory");

    short8 bf_[8];
    #pragma unroll
    for (int nt = 0; nt < 8; ++nt)
      bf_[nt] = *(const short8*)(wseg + cur * 8192 + (nt * 16 + n16) * 64 + quad * 16);

    // prefetch tile t+1 into the other wave-local buffer (no barrier needed:
    // that buffer's reads completed before MFMA(t-1), which precedes this)
    if (t < 63) stage_b(cur ^ 1, k0 + 32);

    // producer: THIS lane's A-fragment values (row myrow, cols k0+quad*8..+8)
    float4 va = *(const float4*)((const char*)s2_lds + (k0 + quad * 8) * 4);
    float4 vb = *(const float4*)((const char*)s2_lds + (k0 + quad * 8) * 4 + 16);
    float v[8] = {va.x, va.y, va.z, va.w, vb.x, vb.y, vb.z, vb.w};
    #pragma unroll
    for (int jj = 0; jj < 8; ++jj) {
      float s = s1v + v[jj];
      float l = fmaxf(s, ALPHA_ * s);                       // leaky_relu
      float u = fmaf(l, uscale, ubias);                     // u = -e_norm
      v[jj] = __builtin_amdgcn_rcpf(1.0f + __expf(u));      // sigmoid(e_norm)
    }
    // att store, dedup'd across the wn pair: wn=0 low half, wn=1 high half
    if (wn == 0) nt_store4(attrow + k0 + quad * 8,     (f32x4){v[0], v[1], v[2], v[3]});
    else         nt_store4(attrow + k0 + quad * 8 + 4, (f32x4){v[4], v[5], v[6], v[7]});

    short8 af;
    af[0] = (short)f2bf(v[0]); af[1] = (short)f2bf(v[1]);
    af[2] = (short)f2bf(v[2]); af[3] = (short)f2bf(v[3]);
    af[4] = (short)f2bf(v[4]); af[5] = (short)f2bf(v[5]);
    af[6] = (short)f2bf(v[6]); af[7] = (short)f2bf(v[7]);

    #pragma unroll
    for (int nt = 0; nt < 8; ++nt)
      acc[nt] = __builtin_amdgcn_mfma_f32_16x16x32_bf16(af, bf_[nt], acc[nt], 0, 0, 0);
  }

  // epilogue: ELU + nontemporal store h_prime.
  // wave (wm,wn): rows i0+16wm+quad*4+rg, cols 128wn+nt*16+n16
  float* hp = hprime + ((size_t)(b * N_ + i0)) * F_;
  #pragma unroll
  for (int nt = 0; nt < 8; ++nt) {
    int fcol = 128 * wn + nt * 16 + n16;
    int irow = 16 * wm + quad * 4;
    #pragma unroll
    for (int rg = 0; rg < 4; ++rg) {
      float x = acc[nt][rg];
      float y = x > 0.0f ? x : (__expf(x) - 1.0f);
      __builtin_nontemporal_store(y, hp + (size_t)(irow + rg) * F_ + fcol);
    }
  }
}

// ---------------- launch ----------------
extern "C" void kernel_launch(void* const* d_in, const int* in_sizes, int n_in,
                              void* d_out, int out_size, void* d_ws, size_t ws_size,
                              hipStream_t stream) {
  const float* inp  = (const float*)d_in[0];
  // d_in[1] = adj: unused by the reference computation
  const float* W    = (const float*)d_in[2];
  const float* avec = (const float*)d_in[3];

  float* hprime = (float*)d_out;                         // [8][2048][256]
  float* att    = (float*)d_out + (size_t)B_ * N_ * F_;  // [8][2048][2048]

  char* ws = (char*)d_ws;
  unsigned short* WT = (unsigned short*)ws;                           // 128 KB
  unsigned short* hT = (unsigned short*)(ws + 131072);                // 8 MB
  float* s1          = (float*)(ws + 131072 + 8388608);               // 64 KB
  float* s2          = s1 + BN_;                                      // 64 KB
  uint32_t* maxk     = (uint32_t*)(s2 + BN_);                         // 16 u32
  uint32_t* mink     = maxk + 16;                                     // 16 u32

  k_cvt_w<<<F_, F_, 0, stream>>>(W, WT, maxk, mink);
  k_gemm1<<<BN_ / 64, 256, 0, stream>>>(inp, WT, avec, hT, s1, s2, maxk, mink);
  k_gemm2<<<512, 256, 0, stream>>>(hT, s1, s2, maxk, mink, hprime, att);
}

// Round 8
// 283.347 us; speedup vs baseline: 1.2156x; 1.2156x over previous
//
#include <hip/hip_runtime.h>
#include <stdint.h>

#define B_   8
#define N_   2048
#define F_   256
#define BN_  (B_ * N_)
#define ALPHA_ 0.2f

typedef __attribute__((ext_vector_type(8))) short  short8;
typedef __attribute__((ext_vector_type(4))) float  f32x4;

__device__ __forceinline__ unsigned short f2bf(float x) {
  uint32_t u = __float_as_uint(x);
  uint32_t r = (u + 0x7fffu + ((u >> 16) & 1u)) >> 16;  // RNE
  return (unsigned short)r;
}

// monotone float -> uint key (order-preserving), and inverse
__device__ __forceinline__ uint32_t fkey(float f) {
  uint32_t b = __float_as_uint(f);
  return b ^ (uint32_t)(((int32_t)b >> 31) | (int32_t)0x80000000);
}
__device__ __forceinline__ float ikey(uint32_t k) {
  uint32_t b = (k & 0x80000000u) ? (k ^ 0x80000000u) : ~k;
  return __uint_as_float(b);
}

// nontemporal 16B store (only used where sectors are fully covered)
__device__ __forceinline__ void nt_store4(float* p, f32x4 v) {
  __builtin_nontemporal_store(v, (f32x4*)p);
}

// ============================================================================
// Fragment-major tile layout (the round-7 counter-driven change):
//   a 16(f) x 32(k) bf16 tile = 1024 B = one wave MFMA-B fragment.
//   lane l's 16 B live at tile_base + l*16 and hold
//   f = 16*f0 + (l&15),  k = 32*kb + (l>>4)*8 + e   (e = 0..7).
//   => B-fragment load = ONE fully-coalesced global_load_dwordx4, no LDS.
// WT2 : [f0 0..15][kb 0..7]    tile idx = f0*8  + kb
// hT2 : [b][f0 0..15][kb 0..63] tile idx = (b*16+f0)*64 + kb
// ============================================================================

// ---------------- W -> WT2 fragment-major bf16 + key-atomic init ----------------
__global__ void k_cvt_w(const float* __restrict__ W, unsigned short* __restrict__ WT2,
                        uint32_t* __restrict__ maxk, uint32_t* __restrict__ mink) {
  int k = blockIdx.x, n = threadIdx.x;  // W[k][n], f = n
  if (k == 0 && n < 16) { maxk[n] = 0u; mink[n] = 0xFFFFFFFFu; }
  int idx = (((n >> 4) * 8 + (k >> 5)) << 9)              // tile base (ushorts)
          + ((((k >> 3) & 3) << 4) + (n & 15)) * 8        // lane L = quad*16 + n16
          + (k & 7);                                      // element
  WT2[idx] = f2bf(W[k * F_ + n]);
}

// ---------------- GEMM1 v5: h = inp @ W.
// A: verified LDS staging path (cvt in-register, 2 barriers/iter).
// B: register-direct coalesced frags from WT2 (L2-resident), double-buffered
//    -> no global_load_lds, no B LDS traffic at all.
// Epilogue: Trans transpose (unchanged math) -> hT2 fragment-major stores
//    (1024 B coalesced per wave per pass). LDS 40 KB -> 2 blocks/CU. ----------
__launch_bounds__(256, 2)
__global__ void k_gemm1(const float* __restrict__ inp,            // [BN][F] f32
                        const unsigned short* __restrict__ WT2,   // fragment-major
                        const float* __restrict__ avec,           // [2F]
                        unsigned short* __restrict__ hT2,         // fragment-major
                        float* __restrict__ s1g, float* __restrict__ s2g,
                        uint32_t* __restrict__ maxk, uint32_t* __restrict__ mink) {
  __shared__ __align__(16) unsigned short Atile[64 * 32];   // 4 KB
  __shared__ __align__(16) unsigned short Trans[256 * 72];  // 36 KB
  __shared__ float s1_lds[64], s2_lds[64];

  const int tid  = threadIdx.x;
  const int wave = tid >> 6, lane = tid & 63;
  const int n16  = lane & 15, quad = lane >> 4;
  const int i0   = blockIdx.x * 64;
  const int b    = i0 >> 11;  // batch (2048 rows each; 64 | 2048)

  if (tid < 64) { s1_lds[tid] = 0.0f; s2_lds[tid] = 0.0f; }

  f32x4 acc[4][4];
  #pragma unroll
  for (int mt = 0; mt < 4; ++mt)
    #pragma unroll
    for (int nt = 0; nt < 4; ++nt) acc[mt][nt] = (f32x4){0.f, 0.f, 0.f, 0.f};

  // this wave's B frags: f0 = wave*4 + nt  ->  base + (nt*8 + kb)*512 ushorts
  const unsigned short* wbase = WT2 + (size_t)(wave * 32) * 512 + lane * 8;

  short8 bfA[4], bfB[4];
  #pragma unroll
  for (int nt = 0; nt < 4; ++nt)
    bfA[nt] = *(const short8*)(wbase + (nt * 8 + 0) * 512);

  auto body = [&](int t, short8* bfc, short8* bfn) {
    const int k0 = t << 5;
    {  // stage A from f32 inp: convert in-register, ds_write_b128
      int r = tid >> 2, cp = tid & 3;
      const float* gp = inp + (size_t)(i0 + r) * F_ + k0 + cp * 8;
      float4 va = *(const float4*)gp;
      float4 vb = *(const float4*)(gp + 4);
      short8 sv;
      sv[0] = (short)f2bf(va.x); sv[1] = (short)f2bf(va.y);
      sv[2] = (short)f2bf(va.z); sv[3] = (short)f2bf(va.w);
      sv[4] = (short)f2bf(vb.x); sv[5] = (short)f2bf(vb.y);
      sv[6] = (short)f2bf(vb.z); sv[7] = (short)f2bf(vb.w);
      *(short8*)((char*)Atile + r * 64 + cp * 16) = sv;
    }
    __syncthreads();

    short8 af[4];
    #pragma unroll
    for (int mt = 0; mt < 4; ++mt)
      af[mt] = *(const short8*)((const char*)Atile + ((mt * 16 + n16) * 64 + quad * 16));

    if (t < 7) {  // prefetch next-iter B frags into the other register buffer
      #pragma unroll
      for (int nt = 0; nt < 4; ++nt)
        bfn[nt] = *(const short8*)(wbase + (nt * 8 + t + 1) * 512);
    }

    #pragma unroll
    for (int mt = 0; mt < 4; ++mt)
      #pragma unroll
      for (int nt = 0; nt < 4; ++nt)
        acc[mt][nt] = __builtin_amdgcn_mfma_f32_16x16x32_bf16(af[mt], bfc[nt], acc[mt][nt], 0, 0, 0);
    __syncthreads();
  };

  #pragma unroll
  for (int tt = 0; tt < 8; tt += 2) {
    body(tt, bfA, bfB);
    body(tt + 1, bfB, bfA);
  }

  // ---- epilogue ----
  #pragma unroll
  for (int mt = 0; mt < 4; ++mt)
    #pragma unroll
    for (int nt = 0; nt < 4; ++nt) {
      int f = (wave << 6) + (nt << 4) + n16;
      int i = (mt << 4) + (quad << 2);
      ushort4 pk;
      pk.x = f2bf(acc[mt][nt][0]); pk.y = f2bf(acc[mt][nt][1]);
      pk.z = f2bf(acc[mt][nt][2]); pk.w = f2bf(acc[mt][nt][3]);
      *(ushort4*)(Trans + f * 72 + i) = pk;
    }

  float a1v[4], a2v[4];
  #pragma unroll
  for (int nt = 0; nt < 4; ++nt) {
    int f = (wave << 6) + (nt << 4) + n16;
    a1v[nt] = avec[f];
    a2v[nt] = avec[F_ + f];
  }
  #pragma unroll
  for (int mt = 0; mt < 4; ++mt) {
    float s1p[4] = {0, 0, 0, 0}, s2p[4] = {0, 0, 0, 0};
    #pragma unroll
    for (int nt = 0; nt < 4; ++nt)
      #pragma unroll
      for (int rg = 0; rg < 4; ++rg) {
        s1p[rg] = fmaf(acc[mt][nt][rg], a1v[nt], s1p[rg]);
        s2p[rg] = fmaf(acc[mt][nt][rg], a2v[nt], s2p[rg]);
      }
    #pragma unroll
    for (int rg = 0; rg < 4; ++rg) {
      float v1 = s1p[rg], v2 = s2p[rg];
      #pragma unroll
      for (int off = 1; off < 16; off <<= 1) {
        v1 += __shfl_xor(v1, off);
        v2 += __shfl_xor(v2, off);
      }
      if (n16 == 0) {
        atomicAdd(&s1_lds[(mt << 4) + (quad << 2) + rg], v1);
        atomicAdd(&s2_lds[(mt << 4) + (quad << 2) + rg], v2);
      }
    }
  }
  __syncthreads();

  // hT2 fragment-major store: 8 passes x (1024 B coalesced per wave)
  // pass p, wave w: tile (f0 = 2p + (w>>1), kb = kb0 + (w&1))
  const int kb0 = (i0 & 2047) >> 5;
  #pragma unroll
  for (int p = 0; p < 8; ++p) {
    int f0  = p * 2 + (wave >> 1);
    int kbl = wave & 1;
    short8 v = *(const short8*)(Trans + (16 * f0 + (lane & 15)) * 72 + kbl * 32 + (lane >> 4) * 8);
    *(short8*)(hT2 + (size_t)((b * 16 + f0) * 64 + kb0 + kbl) * 512 + lane * 8) = v;
  }

  if (tid < 64) {
    float v1 = s1_lds[tid], v2 = s2_lds[tid];
    s1g[i0 + tid] = v1;
    s2g[i0 + tid] = v2;
    float mn1 = v1, mx1 = v1, mn2 = v2, mx2 = v2;
    #pragma unroll
    for (int off = 1; off < 64; off <<= 1) {
      mn1 = fminf(mn1, __shfl_xor(mn1, off));
      mx1 = fmaxf(mx1, __shfl_xor(mx1, off));
      mn2 = fminf(mn2, __shfl_xor(mn2, off));
      mx2 = fmaxf(mx2, __shfl_xor(mx2, off));
    }
    if (tid == 0) {
      atomicMax(&maxk[b * 2 + 0], fkey(mx1));
      atomicMax(&maxk[b * 2 + 1], fkey(mx2));
      atomicMin(&mink[b * 2 + 0], fkey(mn1));
      atomicMin(&mink[b * 2 + 1], fkey(mn2));
    }
  }
}

// ---------------- GEMM2 v5: ZERO LDS, ZERO barriers, ZERO manual waitcnt.
// Wave (wm,wn) owns rows 16wm..+15, cols 128wn..+127 (v4b layout, HW-verified).
// B frags load register-direct from fragment-major hT2 (coalesced 1024 B,
// L2-resident), double-buffered with a FULL-ITERATION prefetch window; s2
// values prefetched the same way; compiler tracks all waits per-register.
// att stores: wn=0 wave stores full 32 B/lane (2 dwordx4), NORMAL stores so
// L2 write-combines the interleaved quad pieces into full lines (fixes v4b's
// 1.8x write amplification from scattered nt stores). ----------------
__launch_bounds__(256, 2)
__global__ void k_gemm2(const unsigned short* __restrict__ hT2,  // fragment-major
                        const float* __restrict__ s1, const float* __restrict__ s2,
                        const uint32_t* __restrict__ maxk, const uint32_t* __restrict__ mink,
                        float* __restrict__ hprime,  // [B][N][F]
                        float* __restrict__ att) {   // [B][N][N]
  const int tid  = threadIdx.x;
  const int wave = tid >> 6, lane = tid & 63;
  const int n16  = lane & 15, quad = lane >> 4;
  const int wm   = wave >> 1, wn = wave & 1;
  const int blk  = blockIdx.x;
  const int b    = blk & 7;            // batch = blk%8 -> XCD-local hT2_b in L2
  const int i0   = (blk >> 3) * 32;    // 32-row tile within batch

  float mx1 = ikey(maxk[b * 2 + 0]), mx2 = ikey(maxk[b * 2 + 1]);
  float mn1 = ikey(mink[b * 2 + 0]), mn2 = ikey(mink[b * 2 + 1]);
  float smn = mn1 + mn2, smx = mx1 + mx2;
  float emn = fmaxf(smn, ALPHA_ * smn);
  float emx = fmaxf(smx, ALPHA_ * smx);
  float scale  = 30.0f / (emx - emn);
  const float uscale = -scale;                 // u = -e_norm
  const float ubias  = emn * scale + 20.0f;

  const int   myrow = 16 * wm + n16;           // att row this lane computes
  const float s1v   = s1[b * N_ + i0 + myrow];
  const float* s2q  = s2 + b * N_ + quad * 8;  // lane's col base
  float* attrow = att + ((size_t)(b * N_ + i0 + myrow)) * N_;

  // this wave's B frags: f0 = 8*wn + nt -> tile (b*16 + f0)*64 + kb
  const unsigned short* hbase = hT2 + (size_t)((b * 16 + 8 * wn) * 64) * 512 + lane * 8;

  f32x4 acc[8];
  #pragma unroll
  for (int nt = 0; nt < 8; ++nt) acc[nt] = (f32x4){0.f, 0.f, 0.f, 0.f};

  short8 bfA[8], bfB[8];
  float4 vaA, vbA, vaB, vbB;
  #pragma unroll
  for (int nt = 0; nt < 8; ++nt)
    bfA[nt] = *(const short8*)(hbase + (size_t)(nt * 64) * 512);
  vaA = *(const float4*)(s2q);
  vbA = *(const float4*)(s2q + 4);

  auto body = [&](int t, short8* bfc, float4& vac, float4& vbc,
                  short8* bfn, float4& van, float4& vbn) {
    const int k0 = t << 5;

    if (t < 63) {  // prefetch t+1: 8 B frags + this lane's s2 cols (full-iter window)
      #pragma unroll
      for (int nt = 0; nt < 8; ++nt)
        bfn[nt] = *(const short8*)(hbase + (size_t)(nt * 64 + t + 1) * 512);
      van = *(const float4*)(s2q + k0 + 32);
      vbn = *(const float4*)(s2q + k0 + 36);
    }

    // producer: exactly this lane's A-fragment values (row myrow, cols k0+quad*8..+7)
    float v[8] = {vac.x, vac.y, vac.z, vac.w, vbc.x, vbc.y, vbc.z, vbc.w};
    #pragma unroll
    for (int jj = 0; jj < 8; ++jj) {
      float s = s1v + v[jj];
      float l = fmaxf(s, ALPHA_ * s);                       // leaky_relu
      float u = fmaf(l, uscale, ubias);                     // u = -e_norm
      v[jj] = __builtin_amdgcn_rcpf(1.0f + __expf(u));      // sigmoid(e_norm)
    }
    // att store: wn=0 stores the full 32 B (wn pair computes identical rows).
    // NORMAL stores: the two instructions' interleaved 16B pieces merge in L2.
    if (wn == 0) {
      *(f32x4*)(attrow + k0 + quad * 8)     = (f32x4){v[0], v[1], v[2], v[3]};
      *(f32x4*)(attrow + k0 + quad * 8 + 4) = (f32x4){v[4], v[5], v[6], v[7]};
    }

    short8 af;
    af[0] = (short)f2bf(v[0]); af[1] = (short)f2bf(v[1]);
    af[2] = (short)f2bf(v[2]); af[3] = (short)f2bf(v[3]);
    af[4] = (short)f2bf(v[4]); af[5] = (short)f2bf(v[5]);
    af[6] = (short)f2bf(v[6]); af[7] = (short)f2bf(v[7]);

    #pragma unroll
    for (int nt = 0; nt < 8; ++nt)
      acc[nt] = __builtin_amdgcn_mfma_f32_16x16x32_bf16(af, bfc[nt], acc[nt], 0, 0, 0);
  };

  for (int tt = 0; tt < 64; tt += 2) {
    body(tt,     bfA, vaA, vbA, bfB, vaB, vbB);
    body(tt + 1, bfB, vaB, vbB, bfA, vaA, vbA);
  }

  // epilogue: ELU + nt store h_prime (full 64B sectors per instruction).
  // wave (wm,wn): rows i0+16wm+quad*4+rg, cols 128wn+nt*16+n16  (v4b-verified)
  float* hp = hprime + ((size_t)(b * N_ + i0)) * F_;
  #pragma unroll
  for (int nt = 0; nt < 8; ++nt) {
    int fcol = 128 * wn + nt * 16 + n16;
    int irow = 16 * wm + quad * 4;
    #pragma unroll
    for (int rg = 0; rg < 4; ++rg) {
      float x = acc[nt][rg];
      float y = x > 0.0f ? x : (__expf(x) - 1.0f);
      __builtin_nontemporal_store(y, hp + (size_t)(irow + rg) * F_ + fcol);
    }
  }
}

// ---------------- launch ----------------
extern "C" void kernel_launch(void* const* d_in, const int* in_sizes, int n_in,
                              void* d_out, int out_size, void* d_ws, size_t ws_size,
                              hipStream_t stream) {
  const float* inp  = (const float*)d_in[0];
  // d_in[1] = adj: unused by the reference computation
  const float* W    = (const float*)d_in[2];
  const float* avec = (const float*)d_in[3];

  float* hprime = (float*)d_out;                         // [8][2048][256]
  float* att    = (float*)d_out + (size_t)B_ * N_ * F_;  // [8][2048][2048]

  char* ws = (char*)d_ws;
  unsigned short* WT2 = (unsigned short*)ws;                          // 128 KB
  unsigned short* hT2 = (unsigned short*)(ws + 131072);               // 8 MB
  float* s1           = (float*)(ws + 131072 + 8388608);              // 64 KB
  float* s2           = s1 + BN_;                                     // 64 KB
  uint32_t* maxk      = (uint32_t*)(s2 + BN_);                        // 16 u32
  uint32_t* mink      = maxk + 16;                                    // 16 u32

  k_cvt_w<<<F_, F_, 0, stream>>>(W, WT2, maxk, mink);
  k_gemm1<<<BN_ / 64, 256, 0, stream>>>(inp, WT2, avec, hT2, s1, s2, maxk, mink);
  k_gemm2<<<512, 256, 0, stream>>>(hT2, s1, s2, maxk, mink, hprime, att);
}

// Round 9
// 282.784 us; speedup vs baseline: 1.2180x; 1.0020x over previous
//
#include <hip/hip_runtime.h>
#include <stdint.h>

#define B_   8
#define N_   2048
#define F_   256
#define BN_  (B_ * N_)
#define ALPHA_ 0.2f

typedef __attribute__((ext_vector_type(8))) short  short8;
typedef __attribute__((ext_vector_type(4))) float  f32x4;

__device__ __forceinline__ unsigned short f2bf(float x) {
  uint32_t u = __float_as_uint(x);
  uint32_t r = (u + 0x7fffu + ((u >> 16) & 1u)) >> 16;  // RNE
  return (unsigned short)r;
}

// monotone float -> uint key (order-preserving), and inverse
__device__ __forceinline__ uint32_t fkey(float f) {
  uint32_t b = __float_as_uint(f);
  return b ^ (uint32_t)(((int32_t)b >> 31) | (int32_t)0x80000000);
}
__device__ __forceinline__ float ikey(uint32_t k) {
  uint32_t b = (k & 0x80000000u) ? (k ^ 0x80000000u) : ~k;
  return __uint_as_float(b);
}

__device__ __forceinline__ void async_load16(const void* g, void* l) {
  __builtin_amdgcn_global_load_lds(
      (const __attribute__((address_space(1))) uint32_t*)g,
      (__attribute__((address_space(3))) uint32_t*)l, 16, 0, 0);
}

// ============================================================================
// Fragment-major tile layout (R7 counter-driven):
//   a 16(f) x 32(k) bf16 tile = 1024 B = one wave MFMA-B fragment.
//   lane l's 16 B at tile_base + l*16:  f = 16*f0 + (l&15),
//   k = 32*kb + (l>>4)*8 + e.
//   => B load (global OR global_load_lds OR ds_read) is fully coalesced and
//      LDS reads at lane*16 are bank-conflict-free (fixes v2/v4b's 8-way).
// WT2 : tile idx = f0*8  + kb           (f0 0..15, kb 0..7)
// hT2 : tile idx = (b*16+f0)*64 + kb    (f0 0..15, kb 0..63)
// ============================================================================

// ---------------- W -> WT2 fragment-major bf16 + key-atomic init ----------------
__global__ void k_cvt_w(const float* __restrict__ W, unsigned short* __restrict__ WT2,
                        uint32_t* __restrict__ maxk, uint32_t* __restrict__ mink) {
  int k = blockIdx.x, n = threadIdx.x;  // W[k][n], f = n
  if (k == 0 && n < 16) { maxk[n] = 0u; mink[n] = 0xFFFFFFFFu; }
  int idx = (((n >> 4) * 8 + (k >> 5)) << 9)              // tile base (ushorts)
          + ((((k >> 3) & 3) << 4) + (n & 15)) * 8        // lane L = quad*16 + n16
          + (k & 7);                                      // element
  WT2[idx] = f2bf(W[k * F_ + n]);
}

// ---------------- GEMM1 v5 (kept from R8, passed): h = inp @ W.
// A: LDS staging (cvt in-register). B: register-direct coalesced frags from
// WT2, double-buffered. Epilogue -> hT2 fragment-major coalesced stores. ----
__launch_bounds__(256, 2)
__global__ void k_gemm1(const float* __restrict__ inp,            // [BN][F] f32
                        const unsigned short* __restrict__ WT2,   // fragment-major
                        const float* __restrict__ avec,           // [2F]
                        unsigned short* __restrict__ hT2,         // fragment-major
                        float* __restrict__ s1g, float* __restrict__ s2g,
                        uint32_t* __restrict__ maxk, uint32_t* __restrict__ mink) {
  __shared__ __align__(16) unsigned short Atile[64 * 32];   // 4 KB
  __shared__ __align__(16) unsigned short Trans[256 * 72];  // 36 KB
  __shared__ float s1_lds[64], s2_lds[64];

  const int tid  = threadIdx.x;
  const int wave = tid >> 6, lane = tid & 63;
  const int n16  = lane & 15, quad = lane >> 4;
  const int i0   = blockIdx.x * 64;
  const int b    = i0 >> 11;  // batch (2048 rows each; 64 | 2048)

  if (tid < 64) { s1_lds[tid] = 0.0f; s2_lds[tid] = 0.0f; }

  f32x4 acc[4][4];
  #pragma unroll
  for (int mt = 0; mt < 4; ++mt)
    #pragma unroll
    for (int nt = 0; nt < 4; ++nt) acc[mt][nt] = (f32x4){0.f, 0.f, 0.f, 0.f};

  // this wave's B frags: f0 = wave*4 + nt  ->  base + (nt*8 + kb)*512 ushorts
  const unsigned short* wbase = WT2 + (size_t)(wave * 32) * 512 + lane * 8;

  short8 bfA[4], bfB[4];
  #pragma unroll
  for (int nt = 0; nt < 4; ++nt)
    bfA[nt] = *(const short8*)(wbase + (nt * 8 + 0) * 512);

  auto body = [&](int t, short8* bfc, short8* bfn) {
    const int k0 = t << 5;
    {  // stage A from f32 inp: convert in-register, ds_write_b128
      int r = tid >> 2, cp = tid & 3;
      const float* gp = inp + (size_t)(i0 + r) * F_ + k0 + cp * 8;
      float4 va = *(const float4*)gp;
      float4 vb = *(const float4*)(gp + 4);
      short8 sv;
      sv[0] = (short)f2bf(va.x); sv[1] = (short)f2bf(va.y);
      sv[2] = (short)f2bf(va.z); sv[3] = (short)f2bf(va.w);
      sv[4] = (short)f2bf(vb.x); sv[5] = (short)f2bf(vb.y);
      sv[6] = (short)f2bf(vb.z); sv[7] = (short)f2bf(vb.w);
      *(short8*)((char*)Atile + r * 64 + cp * 16) = sv;
    }
    __syncthreads();

    short8 af[4];
    #pragma unroll
    for (int mt = 0; mt < 4; ++mt)
      af[mt] = *(const short8*)((const char*)Atile + ((mt * 16 + n16) * 64 + quad * 16));

    if (t < 7) {  // prefetch next-iter B frags into the other register buffer
      #pragma unroll
      for (int nt = 0; nt < 4; ++nt)
        bfn[nt] = *(const short8*)(wbase + (nt * 8 + t + 1) * 512);
    }

    #pragma unroll
    for (int mt = 0; mt < 4; ++mt)
      #pragma unroll
      for (int nt = 0; nt < 4; ++nt)
        acc[mt][nt] = __builtin_amdgcn_mfma_f32_16x16x32_bf16(af[mt], bfc[nt], acc[mt][nt], 0, 0, 0);
    __syncthreads();
  };

  #pragma unroll
  for (int tt = 0; tt < 8; tt += 2) {
    body(tt, bfA, bfB);
    body(tt + 1, bfB, bfA);
  }

  // ---- epilogue ----
  #pragma unroll
  for (int mt = 0; mt < 4; ++mt)
    #pragma unroll
    for (int nt = 0; nt < 4; ++nt) {
      int f = (wave << 6) + (nt << 4) + n16;
      int i = (mt << 4) + (quad << 2);
      ushort4 pk;
      pk.x = f2bf(acc[mt][nt][0]); pk.y = f2bf(acc[mt][nt][1]);
      pk.z = f2bf(acc[mt][nt][2]); pk.w = f2bf(acc[mt][nt][3]);
      *(ushort4*)(Trans + f * 72 + i) = pk;
    }

  float a1v[4], a2v[4];
  #pragma unroll
  for (int nt = 0; nt < 4; ++nt) {
    int f = (wave << 6) + (nt << 4) + n16;
    a1v[nt] = avec[f];
    a2v[nt] = avec[F_ + f];
  }
  #pragma unroll
  for (int mt = 0; mt < 4; ++mt) {
    float s1p[4] = {0, 0, 0, 0}, s2p[4] = {0, 0, 0, 0};
    #pragma unroll
    for (int nt = 0; nt < 4; ++nt)
      #pragma unroll
      for (int rg = 0; rg < 4; ++rg) {
        s1p[rg] = fmaf(acc[mt][nt][rg], a1v[nt], s1p[rg]);
        s2p[rg] = fmaf(acc[mt][nt][rg], a2v[nt], s2p[rg]);
      }
    #pragma unroll
    for (int rg = 0; rg < 4; ++rg) {
      float v1 = s1p[rg], v2 = s2p[rg];
      #pragma unroll
      for (int off = 1; off < 16; off <<= 1) {
        v1 += __shfl_xor(v1, off);
        v2 += __shfl_xor(v2, off);
      }
      if (n16 == 0) {
        atomicAdd(&s1_lds[(mt << 4) + (quad << 2) + rg], v1);
        atomicAdd(&s2_lds[(mt << 4) + (quad << 2) + rg], v2);
      }
    }
  }
  __syncthreads();

  // hT2 fragment-major store: 8 passes x (1024 B coalesced per wave)
  const int kb0 = (i0 & 2047) >> 5;
  #pragma unroll
  for (int p = 0; p < 8; ++p) {
    int f0  = p * 2 + (wave >> 1);
    int kbl = wave & 1;
    short8 v = *(const short8*)(Trans + (16 * f0 + (lane & 15)) * 72 + kbl * 32 + (lane >> 4) * 8);
    *(short8*)(hT2 + (size_t)((b * 16 + f0) * 64 + kb0 + kbl) * 512 + lane * 8) = v;
  }

  if (tid < 64) {
    float v1 = s1_lds[tid], v2 = s2_lds[tid];
    s1g[i0 + tid] = v1;
    s2g[i0 + tid] = v2;
    float mn1 = v1, mx1 = v1, mn2 = v2, mx2 = v2;
    #pragma unroll
    for (int off = 1; off < 64; off <<= 1) {
      mn1 = fminf(mn1, __shfl_xor(mn1, off));
      mx1 = fmaxf(mx1, __shfl_xor(mx1, off));
      mn2 = fminf(mn2, __shfl_xor(mn2, off));
      mx2 = fmaxf(mx2, __shfl_xor(mx2, off));
    }
    if (tid == 0) {
      atomicMax(&maxk[b * 2 + 0], fkey(mx1));
      atomicMax(&maxk[b * 2 + 1], fkey(mx2));
      atomicMin(&mink[b * 2 + 0], fkey(mn1));
      atomicMin(&mink[b * 2 + 1], fkey(mn2));
    }
  }
}

// ---------------- GEMM2 v6: the R2-proven counted-vmcnt LDS pipeline (v2),
// ported to fragment-major hT2.
//  - stage_b: 4 global_load_lds per wave; HW dest (base + lane*16) IS the
//    fragment layout -> staged tile is ready to ds_read at lane*16.
//  - B frag LDS reads at lane*16: contiguous, bank-conflict-free (v2/v4b's
//    8-way pattern eliminated; R7 showed 4.2M conflicts/dispatch).
//  - per iter: producer (s2 from LDS, no vmem loads) -> att store (NORMAL,
//    L2 write-combines; fixes nt-scatter 1.8x write amplification) ->
//    Atile ds_write -> vmcnt(1)+lgkmcnt(0) -> barrier -> stage(t+1) ->
//    ds_read A/B -> 8 MFMA.
//  - vmcnt(1): at iter-t wait, queue = [store(t-1)?, stage(t)x4, store(t)];
//    drains stage(t)x4 (+ older store), keeps store(t) in flight one iter.
// LDS: 2x16KB B + 2x2KB A + 8KB s2 = 44KB -> 2 blocks/CU. ----------------
__launch_bounds__(256, 2)
__global__ void k_gemm2(const unsigned short* __restrict__ hT2,  // fragment-major
                        const float* __restrict__ s1, const float* __restrict__ s2,
                        const uint32_t* __restrict__ maxk, const uint32_t* __restrict__ mink,
                        float* __restrict__ hprime,  // [B][N][F]
                        float* __restrict__ att) {   // [B][N][N]
  __shared__ __align__(16) char Btile[2][16384];           // 2 x 16 KB
  __shared__ __align__(16) unsigned short Atile[2][1024];  // 2 x 2 KB
  __shared__ __align__(16) float s2_lds[N_];               // 8 KB

  const int tid  = threadIdx.x;
  const int wave = tid >> 6, lane = tid & 63;
  const int n16  = lane & 15, quad = lane >> 4;
  const int blk  = blockIdx.x;
  const int b    = blk & 7;            // batch = blk%8 -> XCD-local hT2_b in L2
  const int i0   = (blk >> 3) * 32;    // 32-row tile within batch

  float mx1 = ikey(maxk[b * 2 + 0]), mx2 = ikey(maxk[b * 2 + 1]);
  float mn1 = ikey(mink[b * 2 + 0]), mn2 = ikey(mink[b * 2 + 1]);
  float smn = mn1 + mn2, smx = mx1 + mx2;
  float emn = fmaxf(smn, ALPHA_ * smn);
  float emx = fmaxf(smx, ALPHA_ * smx);
  float scale  = 30.0f / (emx - emn);
  const float uscale = -scale;                 // u = -e_norm
  const float ubias  = emn * scale + 20.0f;

  const int r_att = tid >> 3;   // 0..31
  const int c_att = tid & 7;    // j-chunk of 4
  const float s1v = s1[b * N_ + i0 + r_att];
  const float* s2b = s2 + b * N_;
  float* attrow = att + ((size_t)(b * N_ + i0 + r_att)) * N_;

  // stage one k-step (16 tiles, kb fixed): wave stages its own 4 MFMA tiles.
  auto stage_b = [&](int buf_, int kb) {
    #pragma unroll
    for (int g = 0; g < 4; ++g) {
      int f0 = wave * 4 + g;
      async_load16(hT2 + ((size_t)((b * 16 + f0) * 64 + kb) << 9) + lane * 8,
                   (char*)Btile + buf_ * 16384 + (f0 << 10));
    }
  };

  // ---- prologue: s2 row (8 KB) + stage(0); one full drain (once) ----
  #pragma unroll
  for (int it = 0; it < 2; ++it)
    async_load16(s2b + wave * 512 + it * 256 + lane * 4,
                 (char*)s2_lds + wave * 2048 + it * 1024);
  stage_b(0, 0);
  asm volatile("s_waitcnt vmcnt(0) lgkmcnt(0)" ::: "memory");
  __builtin_amdgcn_s_barrier();
  asm volatile("" ::: "memory");

  f32x4 acc[2][4];
  #pragma unroll
  for (int mt = 0; mt < 2; ++mt)
    #pragma unroll
    for (int nt = 0; nt < 4; ++nt) acc[mt][nt] = (f32x4){0.f, 0.f, 0.f, 0.f};

  for (int t = 0; t < 64; ++t) {
    const int cur  = t & 1;
    const int abuf = cur * 2048;  // Atile byte offset
    const int k0   = t << 5;

    // producer: 4 attention values/thread; s2 from LDS (no vmem loads here)
    float4 va = *(const float4*)((const char*)s2_lds + k0 * 4 + c_att * 16);
    float v[4] = {va.x, va.y, va.z, va.w};
    #pragma unroll
    for (int jj = 0; jj < 4; ++jj) {
      float s = s1v + v[jj];
      float l = fmaxf(s, ALPHA_ * s);                       // leaky_relu
      float u = fmaf(l, uscale, ubias);                     // u = -e_norm
      v[jj] = __builtin_amdgcn_rcpf(1.0f + __expf(u));      // sigmoid(e_norm)
    }
    // NORMAL store: 4 lanes' 16B pieces merge to full sectors in L2
    *(f32x4*)(attrow + k0 + c_att * 4) = (f32x4){v[0], v[1], v[2], v[3]};
    ushort4 spk;
    spk.x = f2bf(v[0]); spk.y = f2bf(v[1]); spk.z = f2bf(v[2]); spk.w = f2bf(v[3]);
    *(ushort4*)((char*)Atile + abuf + tid * 8) = spk;  // [r_att][c_att*4]

    // counted wait: drain stage(t)x4 (+ retired older store), keep store(t)
    asm volatile("s_waitcnt vmcnt(1) lgkmcnt(0)" ::: "memory");
    __builtin_amdgcn_s_barrier();
    asm volatile("" ::: "memory");

    // stage t+1 post-barrier; stays in flight across next iter's producer
    if (t < 63) stage_b(cur ^ 1, t + 1);

    short8 af0 = *(const short8*)((const char*)Atile + abuf + n16 * 64 + quad * 16);
    short8 af1 = *(const short8*)((const char*)Atile + abuf + (16 + n16) * 64 + quad * 16);
    short8 bf_[4];
    #pragma unroll
    for (int nt = 0; nt < 4; ++nt)  // conflict-free: contiguous lane*16
      bf_[nt] = *(const short8*)((const char*)Btile + cur * 16384 +
                                 ((wave * 4 + nt) << 10) + lane * 16);

    #pragma unroll
    for (int nt = 0; nt < 4; ++nt) {
      acc[0][nt] = __builtin_amdgcn_mfma_f32_16x16x32_bf16(af0, bf_[nt], acc[0][nt], 0, 0, 0);
      acc[1][nt] = __builtin_amdgcn_mfma_f32_16x16x32_bf16(af1, bf_[nt], acc[1][nt], 0, 0, 0);
    }
  }

  // epilogue: ELU + nontemporal store h_prime (full 64B sectors/instr)
  float* hp = hprime + ((size_t)(b * N_ + i0)) * F_;
  #pragma unroll
  for (int mt = 0; mt < 2; ++mt)
    #pragma unroll
    for (int nt = 0; nt < 4; ++nt) {
      int fcol = (wave << 6) + (nt << 4) + n16;
      int irow = (mt << 4) + (quad << 2);
      #pragma unroll
      for (int rg = 0; rg < 4; ++rg) {
        float x = acc[mt][nt][rg];
        float y = x > 0.0f ? x : (__expf(x) - 1.0f);
        __builtin_nontemporal_store(y, hp + (size_t)(irow + rg) * F_ + fcol);
      }
    }
}

// ---------------- launch ----------------
extern "C" void kernel_launch(void* const* d_in, const int* in_sizes, int n_in,
                              void* d_out, int out_size, void* d_ws, size_t ws_size,
                              hipStream_t stream) {
  const float* inp  = (const float*)d_in[0];
  // d_in[1] = adj: unused by the reference computation
  const float* W    = (const float*)d_in[2];
  const float* avec = (const float*)d_in[3];

  float* hprime = (float*)d_out;                         // [8][2048][256]
  float* att    = (float*)d_out + (size_t)B_ * N_ * F_;  // [8][2048][2048]

  char* ws = (char*)d_ws;
  unsigned short* WT2 = (unsigned short*)ws;                          // 128 KB
  unsigned short* hT2 = (unsigned short*)(ws + 131072);               // 8 MB
  float* s1           = (float*)(ws + 131072 + 8388608);              // 64 KB
  float* s2           = s1 + BN_;                                     // 64 KB
  uint32_t* maxk      = (uint32_t*)(s2 + BN_);                        // 16 u32
  uint32_t* mink      = maxk + 16;                                    // 16 u32

  k_cvt_w<<<F_, F_, 0, stream>>>(W, WT2, maxk, mink);
  k_gemm1<<<BN_ / 64, 256, 0, stream>>>(inp, WT2, avec, hT2, s1, s2, maxk, mink);
  k_gemm2<<<512, 256, 0, stream>>>(hT2, s1, s2, maxk, mink, hprime, att);
}

// Round 11
// 278.079 us; speedup vs baseline: 1.2387x; 1.0169x over previous
//
#include <hip/hip_runtime.h>
#include <stdint.h>

#define B_   8
#define N_   2048
#define F_   256
#define BN_  (B_ * N_)
#define ALPHA_ 0.2f

typedef __attribute__((ext_vector_type(8))) short  short8;
typedef __attribute__((ext_vector_type(4))) float  f32x4;

__device__ __forceinline__ unsigned short f2bf(float x) {
  uint32_t u = __float_as_uint(x);
  uint32_t r = (u + 0x7fffu + ((u >> 16) & 1u)) >> 16;  // RNE
  return (unsigned short)r;
}

// monotone float -> uint key (order-preserving), and inverse
__device__ __forceinline__ uint32_t fkey(float f) {
  uint32_t b = __float_as_uint(f);
  return b ^ (uint32_t)(((int32_t)b >> 31) | (int32_t)0x80000000);
}
__device__ __forceinline__ float ikey(uint32_t k) {
  uint32_t b = (k & 0x80000000u) ? (k ^ 0x80000000u) : ~k;
  return __uint_as_float(b);
}

__device__ __forceinline__ void async_load16(const void* g, void* l) {
  __builtin_amdgcn_global_load_lds(
      (const __attribute__((address_space(1))) uint32_t*)g,
      (__attribute__((address_space(3))) uint32_t*)l, 16, 0, 0);
}

// nontemporal 16B store (use ONLY where sectors are fully covered)
__device__ __forceinline__ void nt_store4(float* p, f32x4 v) {
  __builtin_nontemporal_store(v, (f32x4*)p);
}

// ============================================================================
// Fragment-major tile layout (R7 counter-driven; R8/R9-verified correct):
//   a 16(f) x 32(k) bf16 tile = 1024 B = one wave MFMA-B fragment.
//   lane l's 16 B at tile_base + l*16:  f = 16*f0 + (l&15),
//   k = 32*kb + (l>>4)*8 + e.
//   => global_load_lds dest (base + lane*16) IS the layout; LDS reads at
//      lane*16 are bank-conflict-free (v2's 8-way pattern eliminated).
// WT2 : tile idx = f0*8  + kb           (f0 0..15, kb 0..7)
// hT2 : tile idx = (b*16+f0)*64 + kb    (f0 0..15, kb 0..63)
// ============================================================================

// ---------------- W -> WT2 fragment-major bf16 + key-atomic init ----------------
__global__ void k_cvt_w(const float* __restrict__ W, unsigned short* __restrict__ WT2,
                        uint32_t* __restrict__ maxk, uint32_t* __restrict__ mink) {
  int k = blockIdx.x, n = threadIdx.x;  // W[k][n], f = n
  if (k == 0 && n < 16) { maxk[n] = 0u; mink[n] = 0xFFFFFFFFu; }
  int idx = (((n >> 4) * 8 + (k >> 5)) << 9)              // tile base (ushorts)
          + ((((k >> 3) & 3) << 4) + (n & 15)) * 8        // lane L = quad*16 + n16
          + (k & 7);                                      // element
  WT2[idx] = f2bf(W[k * F_ + n]);
}

// ---------------- GEMM1 v6: the R4-proven v4 loop structure (A LDS staging +
// B via global_load_lds DMA, Trans overlay -> 2 blocks/CU), with B staged from
// fragment-major WT2 (conflict-free LDS reads) and the v5 hT2 epilogue. ----
__launch_bounds__(256, 2)
__global__ void k_gemm1(const float* __restrict__ inp,            // [BN][F] f32
                        const unsigned short* __restrict__ WT2,   // fragment-major
                        const float* __restrict__ avec,           // [2F]
                        unsigned short* __restrict__ hT2,         // fragment-major
                        float* __restrict__ s1g, float* __restrict__ s2g,
                        uint32_t* __restrict__ maxk, uint32_t* __restrict__ mink) {
  // loop phase: Atile 4KB @0, Btile 16KB @4096.  epilogue: Trans 36KB @0.
  __shared__ __align__(16) char smem[256 * 72 * 2];  // 36864 B
  __shared__ float s1_lds[64], s2_lds[64];
  unsigned short* Atile = (unsigned short*)smem;  // [64][32]
  char* Btile = smem + 4096;                      // 16 fragment tiles x 1024 B

  const int tid  = threadIdx.x;
  const int wave = tid >> 6, lane = tid & 63;
  const int n16  = lane & 15, quad = lane >> 4;
  const int i0   = blockIdx.x * 64;
  const int b    = i0 >> 11;  // batch (2048 rows each; 64 | 2048)

  if (tid < 64) { s1_lds[tid] = 0.0f; s2_lds[tid] = 0.0f; }

  f32x4 acc[4][4];
  #pragma unroll
  for (int mt = 0; mt < 4; ++mt)
    #pragma unroll
    for (int nt = 0; nt < 4; ++nt) acc[mt][nt] = (f32x4){0.f, 0.f, 0.f, 0.f};

  for (int t = 0; t < 8; ++t) {
    const int k0 = t << 5;
    {  // stage A from f32 inp: convert in-register, ds_write_b128
      int r = tid >> 2, cp = tid & 3;
      const float* gp = inp + (size_t)(i0 + r) * F_ + k0 + cp * 8;
      float4 va = *(const float4*)gp;
      float4 vb = *(const float4*)(gp + 4);
      short8 sv;
      sv[0] = (short)f2bf(va.x); sv[1] = (short)f2bf(va.y);
      sv[2] = (short)f2bf(va.z); sv[3] = (short)f2bf(va.w);
      sv[4] = (short)f2bf(vb.x); sv[5] = (short)f2bf(vb.y);
      sv[6] = (short)f2bf(vb.z); sv[7] = (short)f2bf(vb.w);
      *(short8*)((char*)Atile + r * 64 + cp * 16) = sv;
    }
    // stage B: 4 DMAs/wave from fragment-major WT2 (dest = linear lane*16)
    #pragma unroll
    for (int g = 0; g < 4; ++g) {
      int f0 = wave * 4 + g;
      async_load16(WT2 + ((size_t)(f0 * 8 + t) << 9) + lane * 8,
                   Btile + (f0 << 10));
    }
    __syncthreads();

    short8 af[4], bf_[4];
    #pragma unroll
    for (int mt = 0; mt < 4; ++mt)
      af[mt] = *(const short8*)((const char*)Atile + ((mt * 16 + n16) * 64 + quad * 16));
    #pragma unroll
    for (int nt = 0; nt < 4; ++nt)  // conflict-free: contiguous lane*16
      bf_[nt] = *(const short8*)(Btile + (((wave << 2) + nt) << 10) + lane * 16);
    #pragma unroll
    for (int mt = 0; mt < 4; ++mt)
      #pragma unroll
      for (int nt = 0; nt < 4; ++nt)
        acc[mt][nt] = __builtin_amdgcn_mfma_f32_16x16x32_bf16(af[mt], bf_[nt], acc[mt][nt], 0, 0, 0);
    __syncthreads();  // also orders last Btile reads before Trans overlay below
  }

  // ---- epilogue (Trans overlays loop tiles; safe after final barrier) ----
  unsigned short* Trans = (unsigned short*)smem;  // [256][72]

  #pragma unroll
  for (int mt = 0; mt < 4; ++mt)
    #pragma unroll
    for (int nt = 0; nt < 4; ++nt) {
      int f = (wave << 6) + (nt << 4) + n16;
      int i = (mt << 4) + (quad << 2);
      ushort4 pk;
      pk.x = f2bf(acc[mt][nt][0]); pk.y = f2bf(acc[mt][nt][1]);
      pk.z = f2bf(acc[mt][nt][2]); pk.w = f2bf(acc[mt][nt][3]);
      *(ushort4*)(Trans + f * 72 + i) = pk;
    }

  float a1v[4], a2v[4];
  #pragma unroll
  for (int nt = 0; nt < 4; ++nt) {
    int f = (wave << 6) + (nt << 4) + n16;
    a1v[nt] = avec[f];
    a2v[nt] = avec[F_ + f];
  }
  #pragma unroll
  for (int mt = 0; mt < 4; ++mt) {
    float s1p[4] = {0, 0, 0, 0}, s2p[4] = {0, 0, 0, 0};
    #pragma unroll
    for (int nt = 0; nt < 4; ++nt)
      #pragma unroll
      for (int rg = 0; rg < 4; ++rg) {
        s1p[rg] = fmaf(acc[mt][nt][rg], a1v[nt], s1p[rg]);
        s2p[rg] = fmaf(acc[mt][nt][rg], a2v[nt], s2p[rg]);
      }
    #pragma unroll
    for (int rg = 0; rg < 4; ++rg) {
      float v1 = s1p[rg], v2 = s2p[rg];
      #pragma unroll
      for (int off = 1; off < 16; off <<= 1) {
        v1 += __shfl_xor(v1, off);
        v2 += __shfl_xor(v2, off);
      }
      if (n16 == 0) {
        atomicAdd(&s1_lds[(mt << 4) + (quad << 2) + rg], v1);
        atomicAdd(&s2_lds[(mt << 4) + (quad << 2) + rg], v2);
      }
    }
  }
  __syncthreads();

  // hT2 fragment-major store: 8 passes x (1024 B coalesced per wave)
  const int kb0 = (i0 & 2047) >> 5;
  #pragma unroll
  for (int p = 0; p < 8; ++p) {
    int f0  = p * 2 + (wave >> 1);
    int kbl = wave & 1;
    short8 v = *(const short8*)(Trans + (16 * f0 + (lane & 15)) * 72 + kbl * 32 + (lane >> 4) * 8);
    *(short8*)(hT2 + (size_t)((b * 16 + f0) * 64 + kb0 + kbl) * 512 + lane * 8) = v;
  }

  if (tid < 64) {
    float v1 = s1_lds[tid], v2 = s2_lds[tid];
    s1g[i0 + tid] = v1;
    s2g[i0 + tid] = v2;
    float mn1 = v1, mx1 = v1, mn2 = v2, mx2 = v2;
    #pragma unroll
    for (int off = 1; off < 64; off <<= 1) {
      mn1 = fminf(mn1, __shfl_xor(mn1, off));
      mx1 = fmaxf(mx1, __shfl_xor(mx1, off));
      mn2 = fminf(mn2, __shfl_xor(mn2, off));
      mx2 = fmaxf(mx2, __shfl_xor(mx2, off));
    }
    if (tid == 0) {
      atomicMax(&maxk[b * 2 + 0], fkey(mx1));
      atomicMax(&maxk[b * 2 + 1], fkey(mx2));
      atomicMin(&mink[b * 2 + 0], fkey(mn1));
      atomicMin(&mink[b * 2 + 1], fkey(mn2));
    }
  }
}

// ---------------- GEMM2 v6nt: R9's counted-vmcnt LDS pipeline on fragment-major
// hT2 (conflict-free B reads), with att stores reverted to NONTEMPORAL (the
// R2-proven mode; producer writes are 128B-contiguous per 8 lanes = full
// sectors, and nt keeps the 128MB att stream from evicting hT2 out of L2).
// LDS: 2x16KB B + 2x2KB A + 8KB s2 = 44KB -> 2 blocks/CU. ----------------
__launch_bounds__(256, 2)
__global__ void k_gemm2(const unsigned short* __restrict__ hT2,  // fragment-major
                        const float* __restrict__ s1, const float* __restrict__ s2,
                        const uint32_t* __restrict__ maxk, const uint32_t* __restrict__ mink,
                        float* __restrict__ hprime,  // [B][N][F]
                        float* __restrict__ att) {   // [B][N][N]
  __shared__ __align__(16) char Btile[2][16384];           // 2 x 16 KB
  __shared__ __align__(16) unsigned short Atile[2][1024];  // 2 x 2 KB
  __shared__ __align__(16) float s2_lds[N_];               // 8 KB

  const int tid  = threadIdx.x;
  const int wave = tid >> 6, lane = tid & 63;
  const int n16  = lane & 15, quad = lane >> 4;
  const int blk  = blockIdx.x;
  const int b    = blk & 7;            // batch = blk%8 -> XCD-local hT2_b in L2
  const int i0   = (blk >> 3) * 32;    // 32-row tile within batch

  float mx1 = ikey(maxk[b * 2 + 0]), mx2 = ikey(maxk[b * 2 + 1]);
  float mn1 = ikey(mink[b * 2 + 0]), mn2 = ikey(mink[b * 2 + 1]);
  float smn = mn1 + mn2, smx = mx1 + mx2;
  float emn = fmaxf(smn, ALPHA_ * smn);
  float emx = fmaxf(smx, ALPHA_ * smx);
  float scale  = 30.0f / (emx - emn);
  const float uscale = -scale;                 // u = -e_norm
  const float ubias  = emn * scale + 20.0f;

  const int r_att = tid >> 3;   // 0..31
  const int c_att = tid & 7;    // j-chunk of 4
  const float s1v = s1[b * N_ + i0 + r_att];
  const float* s2b = s2 + b * N_;
  float* attrow = att + ((size_t)(b * N_ + i0 + r_att)) * N_;

  // stage one k-step (16 tiles, kb fixed): wave stages its own 4 MFMA tiles.
  auto stage_b = [&](int buf_, int kb) {
    #pragma unroll
    for (int g = 0; g < 4; ++g) {
      int f0 = wave * 4 + g;
      async_load16(hT2 + ((size_t)((b * 16 + f0) * 64 + kb) << 9) + lane * 8,
                   (char*)Btile + buf_ * 16384 + (f0 << 10));
    }
  };

  // ---- prologue: s2 row (8 KB) + stage(0); one full drain (once) ----
  #pragma unroll
  for (int it = 0; it < 2; ++it)
    async_load16(s2b + wave * 512 + it * 256 + lane * 4,
                 (char*)s2_lds + wave * 2048 + it * 1024);
  stage_b(0, 0);
  asm volatile("s_waitcnt vmcnt(0) lgkmcnt(0)" ::: "memory");
  __builtin_amdgcn_s_barrier();
  asm volatile("" ::: "memory");

  f32x4 acc[2][4];
  #pragma unroll
  for (int mt = 0; mt < 2; ++mt)
    #pragma unroll
    for (int nt = 0; nt < 4; ++nt) acc[mt][nt] = (f32x4){0.f, 0.f, 0.f, 0.f};

  for (int t = 0; t < 64; ++t) {
    const int cur  = t & 1;
    const int abuf = cur * 2048;  // Atile byte offset
    const int k0   = t << 5;

    // producer: 4 attention values/thread; s2 from LDS (no vmem loads here)
    float4 va = *(const float4*)((const char*)s2_lds + k0 * 4 + c_att * 16);
    float v[4] = {va.x, va.y, va.z, va.w};
    #pragma unroll
    for (int jj = 0; jj < 4; ++jj) {
      float s = s1v + v[jj];
      float l = fmaxf(s, ALPHA_ * s);                       // leaky_relu
      float u = fmaf(l, uscale, ubias);                     // u = -e_norm
      v[jj] = __builtin_amdgcn_rcpf(1.0f + __expf(u));      // sigmoid(e_norm)
    }
    // NONTEMPORAL (R2-proven): 8 lanes cover 128B contiguous -> full sectors,
    // and att's 128MB stream stays out of L2 (hT2 working set lives there).
    nt_store4(attrow + k0 + c_att * 4, (f32x4){v[0], v[1], v[2], v[3]});
    ushort4 spk;
    spk.x = f2bf(v[0]); spk.y = f2bf(v[1]); spk.z = f2bf(v[2]); spk.w = f2bf(v[3]);
    *(ushort4*)((char*)Atile + abuf + tid * 8) = spk;  // [r_att][c_att*4]

    // counted wait: drain stage(t)x4 (+ retired older store), keep store(t)
    asm volatile("s_waitcnt vmcnt(1) lgkmcnt(0)" ::: "memory");
    __builtin_amdgcn_s_barrier();
    asm volatile("" ::: "memory");

    // stage t+1 post-barrier; stays in flight across next iter's producer
    if (t < 63) stage_b(cur ^ 1, t + 1);

    short8 af0 = *(const short8*)((const char*)Atile + abuf + n16 * 64 + quad * 16);
    short8 af1 = *(const short8*)((const char*)Atile + abuf + (16 + n16) * 64 + quad * 16);
    short8 bf_[4];
    #pragma unroll
    for (int nt = 0; nt < 4; ++nt)  // conflict-free: contiguous lane*16
      bf_[nt] = *(const short8*)((const char*)Btile + cur * 16384 +
                                 (((wave << 2) + nt) << 10) + lane * 16);

    #pragma unroll
    for (int nt = 0; nt < 4; ++nt) {
      acc[0][nt] = __builtin_amdgcn_mfma_f32_16x16x32_bf16(af0, bf_[nt], acc[0][nt], 0, 0, 0);
      acc[1][nt] = __builtin_amdgcn_mfma_f32_16x16x32_bf16(af1, bf_[nt], acc[1][nt], 0, 0, 0);
    }
  }

  // epilogue: ELU + nontemporal store h_prime (full 64B sectors/instr)
  float* hp = hprime + ((size_t)(b * N_ + i0)) * F_;
  #pragma unroll
  for (int mt = 0; mt < 2; ++mt)
    #pragma unroll
    for (int nt = 0; nt < 4; ++nt) {
      int fcol = (wave << 6) + (nt << 4) + n16;
      int irow = (mt << 4) + (quad << 2);
      #pragma unroll
      for (int rg = 0; rg < 4; ++rg) {
        float x = acc[mt][nt][rg];
        float y = x > 0.0f ? x : (__expf(x) - 1.0f);
        __builtin_nontemporal_store(y, hp + (size_t)(irow + rg) * F_ + fcol);
      }
    }
}

// ---------------- launch ----------------
extern "C" void kernel_launch(void* const* d_in, const int* in_sizes, int n_in,
                              void* d_out, int out_size, void* d_ws, size_t ws_size,
                              hipStream_t stream) {
  const float* inp  = (const float*)d_in[0];
  // d_in[1] = adj: unused by the reference computation
  const float* W    = (const float*)d_in[2];
  const float* avec = (const float*)d_in[3];

  float* hprime = (float*)d_out;                         // [8][2048][256]
  float* att    = (float*)d_out + (size_t)B_ * N_ * F_;  // [8][2048][2048]

  char* ws = (char*)d_ws;
  unsigned short* WT2 = (unsigned short*)ws;                          // 128 KB
  unsigned short* hT2 = (unsigned short*)(ws + 131072);               // 8 MB
  float* s1           = (float*)(ws + 131072 + 8388608);              // 64 KB
  float* s2           = s1 + BN_;                                     // 64 KB
  uint32_t* maxk      = (uint32_t*)(s2 + BN_);                        // 16 u32
  uint32_t* mink      = maxk + 16;                                    // 16 u32

  k_cvt_w<<<F_, F_, 0, stream>>>(W, WT2, maxk, mink);
  k_gemm1<<<BN_ / 64, 256, 0, stream>>>(inp, WT2, avec, hT2, s1, s2, maxk, mink);
  k_gemm2<<<512, 256, 0, stream>>>(hT2, s1, s2, maxk, mink, hprime, att);
}